// Round 6
// baseline (213.001 us; speedup 1.0000x reference)
//
#include <hip/hip_runtime.h>

#define N_TOK 131072
#define TILE 128             // tokens per block
#define NT_MAX 1040          // N_TOK/TILE + 16 tasks worth of padding tiles
#define XS 136               // X row stride (shorts): 128 + 8 (272 B, 16B-aligned, bank-balanced)
#define HS 264               // H row stride (shorts): 256 + 8 (528 B, 16B-aligned, bank-balanced)

typedef __attribute__((ext_vector_type(8))) short s8v;
typedef __attribute__((ext_vector_type(16))) float f16v;
typedef unsigned short ushort_t;

__device__ __forceinline__ unsigned short f2bf(float x) {
    union { float f; unsigned u; } v; v.f = x;
    unsigned r = v.u + 0x7fffu + ((v.u >> 16) & 1u);   // RNE (prep only)
    return (unsigned short)(r >> 16);
}

// round-half-up pack of two f32 -> packed bf16x2
__device__ __forceinline__ unsigned pk2(float a, float b) {
    union { float f; unsigned u; } x, y; x.f = a; y.f = b;
    return ((x.u + 0x8000u) >> 16) | ((y.u + 0x8000u) & 0xffff0000u);
}

__device__ __forceinline__ float tanh_fast(float x) {
    float e = __expf(2.0f * x);
    return 1.0f - 2.0f / (e + 1.0f);
}

// stored-k index -> physical feature within a 32-block (C-layout-native order):
// s = lh*16 + rg  ->  phys = (rg&3) + 8*(rg>>2) + 4*lh
__device__ __forceinline__ int phi(int s) {
    int lh = s >> 4, rg = s & 15;
    return (rg & 3) + 8 * (rg >> 2) + 4 * lh;
}

// ------------------------------------------------- fused prep + hist
// blocks [0,224): repack weights to bf16 A-fragments of mfma_f32_32x32x16:
//   frag (c, F, kt): lane l, elem j: feature = F*32 + (l&31),
//   k_stored = kt*16 + (l>>5)*8 + j; k_phys = (k_stored&~31) + phi(k_stored&31)
//   for W1/W2 (their K dim is a permuted-stored H), identity for W0.
// blocks [224,288): 16-bin histogram of task[].
__global__ void prep_hist_kernel(const float* __restrict__ W0, const float* __restrict__ W1,
                                 const float* __restrict__ W2,
                                 ushort_t* __restrict__ W0p, ushort_t* __restrict__ W1p,
                                 ushort_t* __restrict__ W2p,
                                 const int* __restrict__ task, int* __restrict__ blockCounts) {
    if (blockIdx.x < 224) {
        int i = blockIdx.x * 256 + threadIdx.x;   // [0, 57344)
        const float* src; ushort_t* dst; int K, N, permk;
        if (i < 16384)      { src = W0; dst = W0p; K = 128; N = 256; permk = 0; }
        else if (i < 49152) { src = W1; dst = W1p; K = 256; N = 256; permk = 1; i -= 16384; }
        else                { src = W2; dst = W2p; K = 256; N = 64;  permk = 1; i -= 49152; }
        int lane = i & 63, fr = i >> 6;           // global fragment index (c-major)
        int KT = K >> 4;
        int fpc = (N >> 5) * KT;                  // frags per copy
        int c = fr / fpc, r = fr % fpc;
        int F = r / KT, kt = r % KT;
        int fphys = F * 32 + (lane & 31);
        s8v pk;
#pragma unroll
        for (int j = 0; j < 8; j++) {
            int ks = kt * 16 + ((lane >> 5) << 3) + j;
            int kp = permk ? ((ks & ~31) + phi(ks & 31)) : ks;
            pk[j] = (short)f2bf(src[((size_t)c * K + kp) * N + fphys]);
        }
        *reinterpret_cast<s8v*>(dst + ((size_t)(fr * 64 + lane) << 3)) = pk;
    } else {
        __shared__ int cnt[16];
        int t = threadIdx.x;
        int hb = blockIdx.x - 224;
        if (t < 16) cnt[t] = 0;
        __syncthreads();
        int base = hb * 2048 + t;
#pragma unroll
        for (int i = 0; i < 8; i++) atomicAdd(&cnt[task[base + i * 256]], 1);
        __syncthreads();
        if (t < 16) blockCounts[hb * 16 + t] = cnt[t];
    }
}

// ------------------------------------------------- fused scan + scatter
__global__ void sort_kernel(const int* __restrict__ task, const int* __restrict__ blockCounts,
                            int* __restrict__ tileTask, int* __restrict__ nT,
                            int* __restrict__ perm) {
    __shared__ int cntLds[1024];
    __shared__ int total[16], pref[16], rank[16];
    __shared__ int tokBase[16], tbase[17];
    int t = threadIdx.x, b = blockIdx.x;
    for (int i = t; i < 1024; i += 256) cntLds[i] = blockCounts[i];
    if (t < 16) rank[t] = 0;
    __syncthreads();
    if (t < 16) {
        int tot = 0, pf = 0;
#pragma unroll
        for (int bb = 0; bb < 64; bb++) {
            int v = cntLds[bb * 16 + t];
            tot += v;
            if (bb < b) pf += v;
        }
        total[t] = tot; pref[t] = pf;
    }
    __syncthreads();
    if (t == 0) {
        int tok = 0, tile = 0;
        for (int k = 0; k < 16; k++) {
            tokBase[k] = tok;
            tbase[k] = tile;
            int ntk = (total[k] + TILE - 1) / TILE;
            tok += ntk * TILE;
            tile += ntk;
        }
        tbase[16] = tile;
        if (b == 0) nT[0] = tile;
    }
    __syncthreads();
    if (b == 0) {
        for (int i = t; i < NT_MAX; i += 256) {
            int tk = 0;
            if (i < tbase[16]) {
#pragma unroll
                for (int k = 0; k < 16; k++) if (i >= tbase[k]) tk = k;
            }
            tileTask[i] = tk;
        }
    }
    int tk[8], my[8];
#pragma unroll
    for (int i = 0; i < 8; i++) {
        int idx = b * 2048 + i * 256 + t;
        tk[i] = task[idx];
        my[i] = atomicAdd(&rank[tk[i]], 1);
    }
#pragma unroll
    for (int i = 0; i < 8; i++) {
        int idx = b * 2048 + i * 256 + t;
        perm[tokBase[tk[i]] + pref[tk[i]] + my[i]] = idx;
    }
}

// ------------------------------------------------- fused MLP (32x32x16, TILE=128)
// Y^T = W^T X^T. Wave grid: L0/L1 (g_t=2, g_f=4): wave w -> token-tile pair
// p=w&1 (tiles 2p,2p+1), feature pair fg=w>>1 (tiles 2fg,2fg+1); acc 2x2 tiles.
// C layout: col(lane&31)=token, row=(rg&3)+8*(rg>>2)+4*(lane>>5)=feature.
// H stored token-major in C-native permuted feature order (phi) -> epilogue is
// two b128 writes per tile; next layer reads b128 B-frags; W1/W2 k-permuted.
// Bias pre-loaded into accumulators. LDS 133 KB -> 1 block/CU, 8 waves.
__launch_bounds__(512, 2)
__global__ void mlp_kernel(const float* __restrict__ x_in,
                           const int* __restrict__ cmap,
                           const float* __restrict__ b0,
                           const float* __restrict__ b1,
                           const float* __restrict__ b2,
                           const ushort_t* __restrict__ W0p,
                           const ushort_t* __restrict__ W1p,
                           const ushort_t* __restrict__ W2p,
                           const int* __restrict__ tileTask,
                           const int* __restrict__ nTp,
                           const int* __restrict__ perm,
                           float* __restrict__ out) {
    __shared__ __align__(16) ushort_t H1[TILE * HS];    // 67584 B
    __shared__ __align__(16) ushort_t XH2[TILE * HS];   // X (stride XS) then H2 (stride HS)
    __shared__ int toks[TILE];

    int b = blockIdx.x;
    if (b >= nTp[0]) return;
    int t = threadIdx.x;
    int task = tileTask[b];
    int c0 = cmap[task], c1 = cmap[16 + task], c2 = cmap[32 + task];

    // ---- stage X: 4 threads/token, f32 -> bf16, token-major (stride XS)
    {
        int r = t >> 2, q = t & 3;
        int tok = perm[b * TILE + r];
        if (q == 0) toks[r] = tok;
        float4 v[8];
        if ((unsigned)tok < (unsigned)N_TOK) {
            const float4* src = reinterpret_cast<const float4*>(x_in) + (size_t)tok * 32 + q * 8;
#pragma unroll
            for (int i = 0; i < 8; i++) v[i] = src[i];
        } else {
#pragma unroll
            for (int i = 0; i < 8; i++) v[i] = make_float4(0.f, 0.f, 0.f, 0.f);
        }
        ushort_t* dst = &XH2[r * XS + q * 32];
#pragma unroll
        for (int h = 0; h < 2; h++) {
            uint4 pk;
            pk.x = pk2(v[4 * h + 0].x, v[4 * h + 0].y); pk.y = pk2(v[4 * h + 0].z, v[4 * h + 0].w);
            pk.z = pk2(v[4 * h + 1].x, v[4 * h + 1].y); pk.w = pk2(v[4 * h + 1].z, v[4 * h + 1].w);
            // note: v[4h],v[4h+1] cover 8 floats -> one uint4 = 8 bf16
            *reinterpret_cast<uint4*>(dst + h * 16) = pk;
            uint4 pk_b;
            pk_b.x = pk2(v[4 * h + 2].x, v[4 * h + 2].y); pk_b.y = pk2(v[4 * h + 2].z, v[4 * h + 2].w);
            pk_b.z = pk2(v[4 * h + 3].x, v[4 * h + 3].y); pk_b.w = pk2(v[4 * h + 3].z, v[4 * h + 3].w);
            *reinterpret_cast<uint4*>(dst + h * 16 + 8) = pk_b;
        }
    }
    __syncthreads();

    int w = t >> 6;
    int lane = t & 63;
    int l31 = lane & 31, lh = lane >> 5;

    // ---- Layer 0: K=128 (kt=8). acc[mi][nt], F=2*fg+mi, tt=2*p+nt.
    {
        int p = w & 1, fg = w >> 1;
        f16v acc[2][2];
#pragma unroll
        for (int mi = 0; mi < 2; mi++) {
            int F = 2 * fg + mi;
#pragma unroll
            for (int g = 0; g < 4; g++) {
                float4 bv = *reinterpret_cast<const float4*>(b0 + c0 * 256 + F * 32 + g * 8 + 4 * lh);
#pragma unroll
                for (int nt = 0; nt < 2; nt++) {
                    acc[mi][nt][g * 4 + 0] = bv.x; acc[mi][nt][g * 4 + 1] = bv.y;
                    acc[mi][nt][g * 4 + 2] = bv.z; acc[mi][nt][g * 4 + 3] = bv.w;
                }
            }
        }
        const ushort_t* Wc = W0p + (size_t)c0 * 32768;
#pragma unroll
        for (int kt = 0; kt < 8; kt++) {
            s8v wa[2];
#pragma unroll
            for (int mi = 0; mi < 2; mi++)
                wa[mi] = *reinterpret_cast<const s8v*>(Wc + ((((2 * fg + mi) * 8 + kt) * 64 + lane) << 3));
            s8v xb[2];
#pragma unroll
            for (int nt = 0; nt < 2; nt++)
                xb[nt] = *reinterpret_cast<const s8v*>(&XH2[((2 * p + nt) * 32 + l31) * XS + kt * 16 + lh * 8]);
#pragma unroll
            for (int mi = 0; mi < 2; mi++)
#pragma unroll
                for (int nt = 0; nt < 2; nt++)
                    acc[mi][nt] = __builtin_amdgcn_mfma_f32_32x32x16_bf16(wa[mi], xb[nt], acc[mi][nt], 0, 0, 0);
        }
#pragma unroll
        for (int mi = 0; mi < 2; mi++) {
            int F = 2 * fg + mi;
#pragma unroll
            for (int nt = 0; nt < 2; nt++) {
                ushort_t* dst = &H1[((2 * p + nt) * 32 + l31) * HS + F * 32 + lh * 16];
                uint4 o;
                o.x = pk2(tanh_fast(acc[mi][nt][0]), tanh_fast(acc[mi][nt][1]));
                o.y = pk2(tanh_fast(acc[mi][nt][2]), tanh_fast(acc[mi][nt][3]));
                o.z = pk2(tanh_fast(acc[mi][nt][4]), tanh_fast(acc[mi][nt][5]));
                o.w = pk2(tanh_fast(acc[mi][nt][6]), tanh_fast(acc[mi][nt][7]));
                *reinterpret_cast<uint4*>(dst) = o;
                uint4 o2;
                o2.x = pk2(tanh_fast(acc[mi][nt][8]),  tanh_fast(acc[mi][nt][9]));
                o2.y = pk2(tanh_fast(acc[mi][nt][10]), tanh_fast(acc[mi][nt][11]));
                o2.z = pk2(tanh_fast(acc[mi][nt][12]), tanh_fast(acc[mi][nt][13]));
                o2.w = pk2(tanh_fast(acc[mi][nt][14]), tanh_fast(acc[mi][nt][15]));
                *reinterpret_cast<uint4*>(dst + 8) = o2;
            }
        }
    }
    __syncthreads();

    // ---- Layer 1: K=256 (kt=16). Read H1, write H2 into XH2 (X dead).
    {
        int p = w & 1, fg = w >> 1;
        f16v acc[2][2];
#pragma unroll
        for (int mi = 0; mi < 2; mi++) {
            int F = 2 * fg + mi;
#pragma unroll
            for (int g = 0; g < 4; g++) {
                float4 bv = *reinterpret_cast<const float4*>(b1 + c1 * 256 + F * 32 + g * 8 + 4 * lh);
#pragma unroll
                for (int nt = 0; nt < 2; nt++) {
                    acc[mi][nt][g * 4 + 0] = bv.x; acc[mi][nt][g * 4 + 1] = bv.y;
                    acc[mi][nt][g * 4 + 2] = bv.z; acc[mi][nt][g * 4 + 3] = bv.w;
                }
            }
        }
        const ushort_t* Wc = W1p + (size_t)c1 * 65536;
#pragma unroll
        for (int kt = 0; kt < 16; kt++) {
            s8v wa[2];
#pragma unroll
            for (int mi = 0; mi < 2; mi++)
                wa[mi] = *reinterpret_cast<const s8v*>(Wc + ((((2 * fg + mi) * 16 + kt) * 64 + lane) << 3));
            s8v xb[2];
#pragma unroll
            for (int nt = 0; nt < 2; nt++)
                xb[nt] = *reinterpret_cast<const s8v*>(&H1[((2 * p + nt) * 32 + l31) * HS + kt * 16 + lh * 8]);
#pragma unroll
            for (int mi = 0; mi < 2; mi++)
#pragma unroll
                for (int nt = 0; nt < 2; nt++)
                    acc[mi][nt] = __builtin_amdgcn_mfma_f32_32x32x16_bf16(wa[mi], xb[nt], acc[mi][nt], 0, 0, 0);
        }
#pragma unroll
        for (int mi = 0; mi < 2; mi++) {
            int F = 2 * fg + mi;
#pragma unroll
            for (int nt = 0; nt < 2; nt++) {
                ushort_t* dst = &XH2[((2 * p + nt) * 32 + l31) * HS + F * 32 + lh * 16];
                uint4 o;
                o.x = pk2(tanh_fast(acc[mi][nt][0]), tanh_fast(acc[mi][nt][1]));
                o.y = pk2(tanh_fast(acc[mi][nt][2]), tanh_fast(acc[mi][nt][3]));
                o.z = pk2(tanh_fast(acc[mi][nt][4]), tanh_fast(acc[mi][nt][5]));
                o.w = pk2(tanh_fast(acc[mi][nt][6]), tanh_fast(acc[mi][nt][7]));
                *reinterpret_cast<uint4*>(dst) = o;
                uint4 o2;
                o2.x = pk2(tanh_fast(acc[mi][nt][8]),  tanh_fast(acc[mi][nt][9]));
                o2.y = pk2(tanh_fast(acc[mi][nt][10]), tanh_fast(acc[mi][nt][11]));
                o2.z = pk2(tanh_fast(acc[mi][nt][12]), tanh_fast(acc[mi][nt][13]));
                o2.w = pk2(tanh_fast(acc[mi][nt][14]), tanh_fast(acc[mi][nt][15]));
                *reinterpret_cast<uint4*>(dst + 8) = o2;
            }
        }
    }
    __syncthreads();

    // ---- Layer 2: K=256 (kt=16), 64 features = 2 F-tiles. Wave: tt=w&3, F=w>>2.
    {
        int tt = w & 3, F = w >> 2;
        f16v acc;
#pragma unroll
        for (int g = 0; g < 4; g++) {
            float4 bv = *reinterpret_cast<const float4*>(b2 + c2 * 64 + F * 32 + g * 8 + 4 * lh);
            acc[g * 4 + 0] = bv.x; acc[g * 4 + 1] = bv.y;
            acc[g * 4 + 2] = bv.z; acc[g * 4 + 3] = bv.w;
        }
        const ushort_t* Wc = W2p + (size_t)c2 * 16384;
#pragma unroll
        for (int kt = 0; kt < 16; kt++) {
            s8v wa = *reinterpret_cast<const s8v*>(Wc + (((F * 16 + kt) * 64 + lane) << 3));
            s8v xb = *reinterpret_cast<const s8v*>(&XH2[(tt * 32 + l31) * HS + kt * 16 + lh * 8]);
            acc = __builtin_amdgcn_mfma_f32_32x32x16_bf16(wa, xb, acc, 0, 0, 0);
        }
        int tok = toks[tt * 32 + l31];
        if ((unsigned)tok < (unsigned)N_TOK) {
#pragma unroll
            for (int g = 0; g < 4; g++) {
                float4 o;
                o.x = acc[g * 4 + 0]; o.y = acc[g * 4 + 1];
                o.z = acc[g * 4 + 2]; o.w = acc[g * 4 + 3];
                *reinterpret_cast<float4*>(out + (size_t)tok * 64 + F * 32 + g * 8 + 4 * lh) = o;
            }
        }
    }
}

// ---------------------------------------------------------------- launch
extern "C" void kernel_launch(void* const* d_in, const int* in_sizes, int n_in,
                              void* d_out, int out_size, void* d_ws, size_t ws_size,
                              hipStream_t stream) {
    const float* inputs = (const float*)d_in[0];
    const int*   task   = (const int*)d_in[1];
    const int*   cmap   = (const int*)d_in[2];
    const float* W0     = (const float*)d_in[3];
    const float* b0     = (const float*)d_in[4];
    const float* W1     = (const float*)d_in[5];
    const float* b1     = (const float*)d_in[6];
    const float* W2     = (const float*)d_in[7];
    const float* b2     = (const float*)d_in[8];
    float* out = (float*)d_out;

    char* ws = (char*)d_ws;
    int* blockCounts = (int*)(ws + 0);            // 4096 B
    int* nT          = (int*)(ws + 4096);         // 4 B
    int* tileTask    = (int*)(ws + 4160);         // 1040*4 = 4160 B
    int* perm        = (int*)(ws + 8320);         // 1040*128*4 = 532480 B
    ushort_t* W0p    = (ushort_t*)(ws + 540800);  // 262144 B
    ushort_t* W1p    = (ushort_t*)(ws + 802944);  // 524288 B
    ushort_t* W2p    = (ushort_t*)(ws + 1327232); // 131072 B -> total ~1.46 MB

    prep_hist_kernel<<<288, 256, 0, stream>>>(W0, W1, W2, W0p, W1p, W2p, task, blockCounts);
    sort_kernel<<<64, 256, 0, stream>>>(task, blockCounts, tileTask, nT, perm);
    mlp_kernel<<<NT_MAX, 512, 0, stream>>>(inputs, cmap, b0, b1, b2,
                                           W0p, W1p, W2p, tileTask, nT, perm, out);
}

// Round 7
// 165.609 us; speedup vs baseline: 1.2862x; 1.2862x over previous
//
#include <hip/hip_runtime.h>

#define N_TOK 131072
#define TILE 32              // tokens per block
#define NT_MAX 4112          // N_TOK/TILE + 16 tasks worth of padding tiles

typedef __attribute__((ext_vector_type(8))) short s8v;
typedef __attribute__((ext_vector_type(4))) float f4v;
typedef unsigned short ushort_t;

__device__ __forceinline__ unsigned short f2bf(float x) {
    union { float f; unsigned u; } v; v.f = x;
    unsigned r = v.u + 0x7fffu + ((v.u >> 16) & 1u);   // RNE (prep only)
    return (unsigned short)(r >> 16);
}

// round-half-up pack of two f32 -> packed bf16x2 via v_perm_b32 (3 VALU ops)
__device__ __forceinline__ unsigned pk2(float a, float b) {
    union { float f; unsigned u; } x, y; x.f = a; y.f = b;
    return __byte_perm(x.u + 0x8000u, y.u + 0x8000u, 0x7632);
}

// tanh via fast exp + fast rcp: mul, exp, add, rcp, fma (no precise-div sequence)
__device__ __forceinline__ float tanh_fast(float x) {
    float e = __expf(2.0f * x);
    float r = __builtin_amdgcn_rcpf(e + 1.0f);
    return __builtin_fmaf(-2.0f, r, 1.0f);
}

// ------------------------------------------------- fused prep + hist
// blocks [0,224): repack weights to bf16 MFMA fragments (one 16B write/thread).
// Fragment r = (ftile*(K>>5)+kt)*64 + lane; elem j holds W[k][n] with
// n = ftile*16 + (lane&15), k = kt*32 + (lane>>4)*8 + j.  (A operand of
// Y^T = W^T X^T.)   blocks [224,288): 16-bin histogram of task[].
__global__ void prep_hist_kernel(const float* __restrict__ W0, const float* __restrict__ W1,
                                 const float* __restrict__ W2,
                                 ushort_t* __restrict__ W0p, ushort_t* __restrict__ W1p,
                                 ushort_t* __restrict__ W2p,
                                 const int* __restrict__ task, int* __restrict__ blockCounts) {
    if (blockIdx.x < 224) {
        int f = blockIdx.x * 256 + threadIdx.x;   // 57344 total fragments
        const float* src; ushort_t* dst; int K, N;
        if (f < 16384)      { src = W0; dst = W0p; K = 128; N = 256; }
        else if (f < 49152) { src = W1; dst = W1p; K = 256; N = 256; f -= 16384; }
        else                { src = W2; dst = W2p; K = 256; N = 64;  f -= 49152; }
        int fpc = (N >> 4) * (K >> 5) * 64;       // fragments per copy
        int c = f / fpc, r = f % fpc;
        int lane = r & 63;
        int kt = (r >> 6) % (K >> 5);
        int ftile = (r >> 6) / (K >> 5);
        int n = ftile * 16 + (lane & 15);
        int kbase = kt * 32 + (lane >> 4) * 8;
        const float* s = src + (size_t)c * K * N + (size_t)kbase * N + n;
        s8v pk;
#pragma unroll
        for (int j = 0; j < 8; j++) pk[j] = (short)f2bf(s[(size_t)j * N]);
        *reinterpret_cast<s8v*>(dst + ((size_t)(c * fpc + r) << 3)) = pk;
    } else {
        __shared__ int cnt[16];
        int t = threadIdx.x;
        int hb = blockIdx.x - 224;
        if (t < 16) cnt[t] = 0;
        __syncthreads();
        int base = hb * 2048 + t;
#pragma unroll
        for (int i = 0; i < 8; i++) atomicAdd(&cnt[task[base + i * 256]], 1);
        __syncthreads();
        if (t < 16) blockCounts[hb * 16 + t] = cnt[t];
    }
}

// ------------------------------------------------- fused scan + scatter
__global__ void sort_kernel(const int* __restrict__ task, const int* __restrict__ blockCounts,
                            int* __restrict__ tileTask, int* __restrict__ nT,
                            int* __restrict__ perm) {
    __shared__ int cntLds[1024];
    __shared__ int total[16], pref[16], rank[16];
    __shared__ int tokBase[16], tbase[17];
    int t = threadIdx.x, b = blockIdx.x;
    for (int i = t; i < 1024; i += 256) cntLds[i] = blockCounts[i];
    if (t < 16) rank[t] = 0;
    __syncthreads();
    if (t < 16) {
        int tot = 0, pf = 0;
#pragma unroll
        for (int bb = 0; bb < 64; bb++) {
            int v = cntLds[bb * 16 + t];
            tot += v;
            if (bb < b) pf += v;
        }
        total[t] = tot; pref[t] = pf;
    }
    __syncthreads();
    if (t == 0) {
        int tok = 0, tile = 0;
        for (int k = 0; k < 16; k++) {
            tokBase[k] = tok;
            tbase[k] = tile;
            int ntk = (total[k] + TILE - 1) / TILE;
            tok += ntk * TILE;
            tile += ntk;
        }
        tbase[16] = tile;
        if (b == 0) nT[0] = tile;
    }
    __syncthreads();
    if (b == 0) {
        for (int i = t; i < NT_MAX; i += 256) {
            int tk = 0;
            if (i < tbase[16]) {
#pragma unroll
                for (int k = 0; k < 16; k++) if (i >= tbase[k]) tk = k;
            }
            tileTask[i] = tk;
        }
    }
    int tk[8], my[8];
#pragma unroll
    for (int i = 0; i < 8; i++) {
        int idx = b * 2048 + i * 256 + t;
        tk[i] = task[idx];
        my[i] = atomicAdd(&rank[tk[i]], 1);
    }
#pragma unroll
    for (int i = 0; i < 8; i++) {
        int idx = b * 2048 + i * 256 + t;
        perm[tokBase[tk[i]] + pref[tk[i]] + my[i]] = idx;
    }
}

// ------------------------------------------------- fused MLP, fragment-major LDS
// Activations stored in exact MFMA-B-fragment order:
//   frag(tt,kt): elem addr = ((tt*(K/32)+kt)*64 + lane)*8 + j,
//   lane = (tok&15) + 16*((k&31)>>3), j = k&7.
// Reads are contiguous 1KB/wave ds_read_b128. Epilogue (C-layout: col=token,
// row=4 consecutive features) writes one b64 per acc tile. Bias pre-loaded
// into accumulators. LDS 32.1KB -> 4 blocks/CU, 32 waves/CU.
__launch_bounds__(512, 8)
__global__ void mlp_kernel(const float* __restrict__ x_in,
                           const int* __restrict__ cmap,
                           const float* __restrict__ b0,
                           const float* __restrict__ b1,
                           const float* __restrict__ b2,
                           const ushort_t* __restrict__ W0p,
                           const ushort_t* __restrict__ W1p,
                           const ushort_t* __restrict__ W2p,
                           const int* __restrict__ tileTask,
                           const int* __restrict__ nTp,
                           const int* __restrict__ perm,
                           float* __restrict__ out) {
    __shared__ __align__(16) ushort_t H1[8192];    // 2 tt * 8 kt * 64 * 8 = 16 KB
    __shared__ __align__(16) ushort_t XH2[8192];   // X: frags [0,8) (8 KB); H2: frags [0,16)
    __shared__ int toks[TILE];

    int b = blockIdx.x;
    if (b >= nTp[0]) return;
    int t = threadIdx.x;
    int task = tileTask[b];
    int c0 = cmap[task], c1 = cmap[16 + task], c2 = cmap[32 + task];

    int w = t >> 6;                 // wave 0..7
    int lane = t & 63;
    int l15 = lane & 15, lq = lane >> 4;

    // ---- stage X: gather + cvt straight into B-fragment order (one b128/thread)
    {
        int r = t >> 4, q = t & 15;            // token r, covers k = q*8..q*8+7
        int tok = perm[b * TILE + r];
        if (q == 0) toks[r] = tok;
        float4 v0 = make_float4(0.f, 0.f, 0.f, 0.f), v1 = v0;
        if ((unsigned)tok < (unsigned)N_TOK) {
            const float4* src = reinterpret_cast<const float4*>(x_in) + (size_t)tok * 32 + q * 2;
            v0 = src[0]; v1 = src[1];
        }
        // frag coords: kt = q>>2, lane' = (r&15) + 16*(q&3), fragid = (r>>4)*4 + kt
        int fragid = (r >> 4) * 4 + (q >> 2);
        int lanep = (r & 15) + 16 * (q & 3);
        uint4 pk;
        pk.x = pk2(v0.x, v0.y); pk.y = pk2(v0.z, v0.w);
        pk.z = pk2(v1.x, v1.y); pk.w = pk2(v1.z, v1.w);
        *reinterpret_cast<uint4*>(&XH2[(fragid * 64 + lanep) << 3]) = pk;
    }
    __syncthreads();

    // ---- Layer 0: H1^T = W0^T X^T. Wave w: feature tiles {2w,2w+1} x 2 token tiles.
    {
        f4v acc[2][2];
#pragma unroll
        for (int mi = 0; mi < 2; mi++) {
            float4 bv = *reinterpret_cast<const float4*>(b0 + c0 * 256 + (2 * w + mi) * 16 + lq * 4);
#pragma unroll
            for (int nt = 0; nt < 2; nt++) {
                acc[mi][nt][0] = bv.x; acc[mi][nt][1] = bv.y;
                acc[mi][nt][2] = bv.z; acc[mi][nt][3] = bv.w;
            }
        }
        const ushort_t* Wc = W0p + (size_t)c0 * 32768;
#pragma unroll
        for (int kt = 0; kt < 4; kt++) {
            s8v wa[2];
#pragma unroll
            for (int mi = 0; mi < 2; mi++)
                wa[mi] = *reinterpret_cast<const s8v*>(Wc + ((((2 * w + mi) * 4 + kt) * 64 + lane) << 3));
            s8v xb[2];
#pragma unroll
            for (int nt = 0; nt < 2; nt++)
                xb[nt] = *reinterpret_cast<const s8v*>(&XH2[((nt * 4 + kt) * 64 + lane) << 3]);
#pragma unroll
            for (int mi = 0; mi < 2; mi++)
#pragma unroll
                for (int nt = 0; nt < 2; nt++)
                    acc[mi][nt] = __builtin_amdgcn_mfma_f32_16x16x32_bf16(wa[mi], xb[nt], acc[mi][nt], 0, 0, 0);
        }
#pragma unroll
        for (int mi = 0; mi < 2; mi++) {
            int ft = 2 * w + mi;
            int kt_h = ft >> 1;
            int lanep = l15 + 16 * ((ft & 1) * 2 + (lq >> 1));
            int j0 = (lq & 1) * 4;
#pragma unroll
            for (int nt = 0; nt < 2; nt++) {
                float t0 = tanh_fast(acc[mi][nt][0]);
                float t1 = tanh_fast(acc[mi][nt][1]);
                float t2 = tanh_fast(acc[mi][nt][2]);
                float t3 = tanh_fast(acc[mi][nt][3]);
                uint2 pk; pk.x = pk2(t0, t1); pk.y = pk2(t2, t3);
                *reinterpret_cast<uint2*>(&H1[(((nt * 8 + kt_h) * 64 + lanep) << 3) + j0]) = pk;
            }
        }
    }
    __syncthreads();

    // ---- Layer 1: H2^T = W1^T H1^T. (H2 overlays X region.)
    {
        f4v acc[2][2];
#pragma unroll
        for (int mi = 0; mi < 2; mi++) {
            float4 bv = *reinterpret_cast<const float4*>(b1 + c1 * 256 + (2 * w + mi) * 16 + lq * 4);
#pragma unroll
            for (int nt = 0; nt < 2; nt++) {
                acc[mi][nt][0] = bv.x; acc[mi][nt][1] = bv.y;
                acc[mi][nt][2] = bv.z; acc[mi][nt][3] = bv.w;
            }
        }
        const ushort_t* Wc = W1p + (size_t)c1 * 65536;
#pragma unroll
        for (int kt = 0; kt < 8; kt++) {
            s8v wa[2];
#pragma unroll
            for (int mi = 0; mi < 2; mi++)
                wa[mi] = *reinterpret_cast<const s8v*>(Wc + ((((2 * w + mi) * 8 + kt) * 64 + lane) << 3));
            s8v xb[2];
#pragma unroll
            for (int nt = 0; nt < 2; nt++)
                xb[nt] = *reinterpret_cast<const s8v*>(&H1[((nt * 8 + kt) * 64 + lane) << 3]);
#pragma unroll
            for (int mi = 0; mi < 2; mi++)
#pragma unroll
                for (int nt = 0; nt < 2; nt++)
                    acc[mi][nt] = __builtin_amdgcn_mfma_f32_16x16x32_bf16(wa[mi], xb[nt], acc[mi][nt], 0, 0, 0);
        }
#pragma unroll
        for (int mi = 0; mi < 2; mi++) {
            int ft = 2 * w + mi;
            int kt_h = ft >> 1;
            int lanep = l15 + 16 * ((ft & 1) * 2 + (lq >> 1));
            int j0 = (lq & 1) * 4;
#pragma unroll
            for (int nt = 0; nt < 2; nt++) {
                float t0 = tanh_fast(acc[mi][nt][0]);
                float t1 = tanh_fast(acc[mi][nt][1]);
                float t2 = tanh_fast(acc[mi][nt][2]);
                float t3 = tanh_fast(acc[mi][nt][3]);
                uint2 pk; pk.x = pk2(t0, t1); pk.y = pk2(t2, t3);
                *reinterpret_cast<uint2*>(&XH2[(((nt * 8 + kt_h) * 64 + lanep) << 3) + j0]) = pk;
            }
        }
    }
    __syncthreads();

    // ---- Layer 2: O^T = W2^T H2^T. 4 mt x 2 nt tiles / 8 waves = 1 tile/wave.
    {
        int mt = w & 3, nt = w >> 2;
        float4 bv = *reinterpret_cast<const float4*>(b2 + c2 * 64 + mt * 16 + lq * 4);
        f4v acc;
        acc[0] = bv.x; acc[1] = bv.y; acc[2] = bv.z; acc[3] = bv.w;
        const ushort_t* Wc = W2p + (size_t)c2 * 16384;
#pragma unroll
        for (int kt = 0; kt < 8; kt++) {
            s8v wa = *reinterpret_cast<const s8v*>(Wc + (((mt * 8 + kt) * 64 + lane) << 3));
            s8v xb = *reinterpret_cast<const s8v*>(&XH2[((nt * 8 + kt) * 64 + lane) << 3]);
            acc = __builtin_amdgcn_mfma_f32_16x16x32_bf16(wa, xb, acc, 0, 0, 0);
        }
        int tok = toks[nt * 16 + l15];
        if ((unsigned)tok < (unsigned)N_TOK) {
            float4 o;
            o.x = acc[0]; o.y = acc[1]; o.z = acc[2]; o.w = acc[3];
            *reinterpret_cast<float4*>(out + (size_t)tok * 64 + mt * 16 + lq * 4) = o;
        }
    }
}

// ---------------------------------------------------------------- launch
extern "C" void kernel_launch(void* const* d_in, const int* in_sizes, int n_in,
                              void* d_out, int out_size, void* d_ws, size_t ws_size,
                              hipStream_t stream) {
    const float* inputs = (const float*)d_in[0];
    const int*   task   = (const int*)d_in[1];
    const int*   cmap   = (const int*)d_in[2];
    const float* W0     = (const float*)d_in[3];
    const float* b0     = (const float*)d_in[4];
    const float* W1     = (const float*)d_in[5];
    const float* b1     = (const float*)d_in[6];
    const float* W2     = (const float*)d_in[7];
    const float* b2     = (const float*)d_in[8];
    float* out = (float*)d_out;

    char* ws = (char*)d_ws;
    int* blockCounts = (int*)(ws + 0);            // 64*16*4 = 4096 B
    int* nT          = (int*)(ws + 4096);         // 4 B
    int* tileTask    = (int*)(ws + 4160);         // 4112*4 = 16448 B
    int* perm        = (int*)(ws + 20608);        // 4112*32*4 = 526336 B
    ushort_t* W0p    = (ushort_t*)(ws + 546944);  // 262144 B
    ushort_t* W1p    = (ushort_t*)(ws + 809088);  // 524288 B
    ushort_t* W2p    = (ushort_t*)(ws + 1333376); // 131072 B -> total ~1.40 MB

    prep_hist_kernel<<<288, 256, 0, stream>>>(W0, W1, W2, W0p, W1p, W2p, task, blockCounts);
    sort_kernel<<<64, 256, 0, stream>>>(task, blockCounts, tileTask, nT, perm);
    mlp_kernel<<<NT_MAX, 512, 0, stream>>>(inputs, cmap, b0, b1, b2,
                                           W0p, W1p, W2p, tileTask, nT, perm, out);
}